// Round 14
// baseline (32.671 us; speedup 1.0000x reference)
//
#include <hip/hip_runtime.h>
#include <math.h>
#include <stdint.h>

#define HH 128
#define WW 128

typedef __fp16 h2 __attribute__((ext_vector_type(2)));
typedef float  f4 __attribute__((ext_vector_type(4)));

__device__ __forceinline__ h2 h2max(h2 a, h2 b) { return __builtin_elementwise_max(a, b); }
__device__ __forceinline__ uint32_t h2u(h2 v) { return __builtin_bit_cast(uint32_t, v); }
__device__ __forceinline__ h2 uh2(uint32_t v) { return __builtin_bit_cast(h2, v); }

#if __has_builtin(__builtin_elementwise_fma)
#define H2FMA(a, b, c) __builtin_elementwise_fma((a), (b), (c))
#else
#define H2FMA(a, b, c) ((a) * (b) + (c))   // contracts to v_pk_fma_f16
#endif

// counted wait + scheduling fence (rule #18)
#define WAITV(n) do { asm volatile("s_waitcnt vmcnt(" #n ")" ::: "memory"); \
                      __builtin_amdgcn_sched_barrier(0); } while (0)

__global__ __launch_bounds__(256) void morpho_kernel(
    const float* __restrict__ x,     // [B,C,128,128]
    const float* __restrict__ wgt,   // [B,C,5,5]
    const float* __restrict__ bias,  // [B,C]
    const float* __restrict__ sign,  // [B]
    float* __restrict__ out)         // [B,C,128,128]
{
    // T1: XCD-contiguous chunks (2048 % 8 == 0 -> bijective)
    const int bid  = blockIdx.x;
    const int blk  = (bid & 7) * 256 + (bid >> 3);
    const int half = blk & 1;        // 64-row half-plane
    const int bc   = blk >> 1;       // plane = b*64 + c
    const int b    = bc >> 6;

    float*       __restrict__ yp = out + (size_t)bc * (HH * WW);
    const float* __restrict__ wp = wgt + bc * 25;

    const float sgn = sign[b];
    const float s   = (fabsf(sgn) >= 1e-7f) ? sgn : 1.0f;
    const float bvs = bias[bc] * s;
    const __fp16 sh = (__fp16)s;
    const h2 s2 = { sh, sh };

    // weights as broadcast f16 pairs -> SGPRs (block-uniform)
    uint32_t wsu[25];
#pragma unroll
    for (int k = 0; k < 25; ++k) {
        const __fp16 wh = (__fp16)wp[k];
        h2 w2 = { wh, wh };
        wsu[k] = (uint32_t)__builtin_amdgcn_readfirstlane((int)h2u(w2));
    }

    const int t  = threadIdx.x;
    const int tx = t & 15;           // 8-col block: cols j0..j0+7
    const int ty = t >> 4;           // 0..15, 4-row tile
    const int j0 = tx * 8;
    const int i0 = half * 64 + ty * 4;
    const int planeOff = bc * (HH * WW);
    const bool mL = (tx > 0);
    const bool mR = (tx < 15);

    // normalize vmcnt to 0 so the counted waits below are exact
    asm volatile("s_waitcnt vmcnt(0)" ::: "memory");

    float4 va[4], vb[4];             // 4-row ring, 2 loads/row (32 B)
    h2 acc[4][4];                    // [out-row][col-pair]

    auto ISSUE = [&](int r8) {
        const int rrow = i0 - 2 + r8;
        const int rc   = min(max(rrow, 0), HH - 1);   // v_med3; masked later
        const float* gp = x + planeOff + rc * WW + j0;
        asm volatile("global_load_dwordx4 %0, %1, off" : "=v"(va[r8 & 3]) : "v"(gp));
        asm volatile("global_load_dwordx4 %0, %1, off" : "=v"(vb[r8 & 3]) : "v"(gp + 4));
    };

    auto CONSUME = [&](int r8) {
        const int  rrow = i0 - 2 + r8;
        const bool rv = ((unsigned)rrow < (unsigned)HH);
        const float4 u = va[r8 & 3];
        const float4 v = vb[r8 & 3];
        // own even pairs E0..E3 (cols j0..j0+7), row-masked (pad -> 0 -> tap = w)
        uint32_t E0 = h2u(__builtin_amdgcn_cvt_pkrtz(u.x, u.y));
        uint32_t E1 = h2u(__builtin_amdgcn_cvt_pkrtz(u.z, u.w));
        uint32_t E2 = h2u(__builtin_amdgcn_cvt_pkrtz(v.x, v.y));
        uint32_t E3 = h2u(__builtin_amdgcn_cvt_pkrtz(v.z, v.w));
        E0 = rv ? E0 : 0u;  E1 = rv ? E1 : 0u;
        E2 = rv ? E2 : 0u;  E3 = rv ? E3 : 0u;
        // halo pairs from 16-lane neighbors, col-masked
        uint32_t eL = (uint32_t)__shfl_up((int)E3, 1, 16);    // cols (j0-2,j0-1)
        uint32_t eR = (uint32_t)__shfl_down((int)E0, 1, 16);  // cols (j0+8,j0+9)
        eL = mL ? eL : 0u;
        eR = mR ? eR : 0u;
        // A[i] = even pair starting at col j0-2+2i; O[i] = odd pair (A[i].y, A[i+1].x)
        const uint32_t A[6] = { eL, E0, E1, E2, E3, eR };
        uint32_t O[5];
#pragma unroll
        for (int k2 = 0; k2 < 5; ++k2) O[k2] = __builtin_amdgcn_alignbit(A[k2 + 1], A[k2], 16);

#pragma unroll
        for (int p = 0; p < 5; ++p) {
            const int oi = r8 - p;   // output row fed by this input row
            if (oi >= 0 && oi < 4) {
                const h2 w0 = uh2(wsu[p * 5 + 0]);
                const h2 w1 = uh2(wsu[p * 5 + 1]);
                const h2 w2 = uh2(wsu[p * 5 + 2]);
                const h2 w3 = uh2(wsu[p * 5 + 3]);
                const h2 w4 = uh2(wsu[p * 5 + 4]);
#pragma unroll
                for (int i = 0; i < 4; ++i) {    // col-pair i = cols (j0+2i, j0+2i+1)
                    const h2 t0 = H2FMA(uh2(A[i]),     s2, w0);
                    const h2 t1 = H2FMA(uh2(O[i]),     s2, w1);
                    const h2 t2 = H2FMA(uh2(A[i + 1]), s2, w2);
                    const h2 t3 = H2FMA(uh2(O[i + 1]), s2, w3);
                    const h2 t4 = H2FMA(uh2(A[i + 2]), s2, w4);
                    h2 mm = h2max(h2max(h2max(t0, t1), h2max(t2, t3)), t4);
                    acc[oi][i] = (p == 0) ? mm : h2max(acc[oi][i], mm);
                }
            }
        }
    };

    // ---- rolling 4-row (8-load) window, compiler-proof ----
    ISSUE(0); ISSUE(1); ISSUE(2); ISSUE(3);
    WAITV(6); CONSUME(0); ISSUE(4);
    WAITV(6); CONSUME(1); ISSUE(5);
    WAITV(6); CONSUME(2); ISSUE(6);
    WAITV(6); CONSUME(3); ISSUE(7);
    WAITV(6); CONSUME(4);
    WAITV(4); CONSUME(5);
    WAITV(2); CONSUME(6);
    WAITV(0); CONSUME(7);

    // ---- epilogue: y = acc*s + bias*s in f32, non-temporal stores ----
#pragma unroll
    for (int a = 0; a < 4; ++a) {
        float* rp = yp + (size_t)(i0 + a) * WW + j0;
        f4 o01, o23;
        o01.x = fmaf((float)acc[a][0][0], s, bvs);
        o01.y = fmaf((float)acc[a][0][1], s, bvs);
        o01.z = fmaf((float)acc[a][1][0], s, bvs);
        o01.w = fmaf((float)acc[a][1][1], s, bvs);
        o23.x = fmaf((float)acc[a][2][0], s, bvs);
        o23.y = fmaf((float)acc[a][2][1], s, bvs);
        o23.z = fmaf((float)acc[a][3][0], s, bvs);
        o23.w = fmaf((float)acc[a][3][1], s, bvs);
        __builtin_nontemporal_store(o01, reinterpret_cast<f4*>(rp));
        __builtin_nontemporal_store(o23, reinterpret_cast<f4*>(rp + 4));
    }
}

extern "C" void kernel_launch(void* const* d_in, const int* in_sizes, int n_in,
                              void* d_out, int out_size, void* d_ws, size_t ws_size,
                              hipStream_t stream) {
    (void)d_ws; (void)ws_size; (void)in_sizes; (void)n_in; (void)out_size;
    const float* x    = (const float*)d_in[0];
    const float* w    = (const float*)d_in[1];
    const float* bias = (const float*)d_in[2];
    const float* sign = (const float*)d_in[3];
    float* out = (float*)d_out;

    morpho_kernel<<<2048, 256, 0, stream>>>(x, w, bias, sign, out);
}

// Round 15
// 27.476 us; speedup vs baseline: 1.1891x; 1.1891x over previous
//
#include <hip/hip_runtime.h>
#include <math.h>
#include <stdint.h>

#define HH 128
#define WW 128

typedef __fp16 h2 __attribute__((ext_vector_type(2)));

__device__ __forceinline__ h2 h2max(h2 a, h2 b) { return __builtin_elementwise_max(a, b); }
__device__ __forceinline__ uint32_t h2u(h2 v) { return __builtin_bit_cast(uint32_t, v); }
__device__ __forceinline__ h2 uh2(uint32_t v) { return __builtin_bit_cast(h2, v); }

#if __has_builtin(__builtin_elementwise_fma)
#define H2FMA(a, b, c) __builtin_elementwise_fma((a), (b), (c))
#else
#define H2FMA(a, b, c) ((a) * (b) + (c))   // contracts to v_pk_fma_f16
#endif

// counted wait + scheduling fence (rule #18)
#define WAITV(n) do { asm volatile("s_waitcnt vmcnt(" #n ")" ::: "memory"); \
                      __builtin_amdgcn_sched_barrier(0); } while (0)

__global__ __launch_bounds__(256) void morpho_kernel(
    const float* __restrict__ x,     // [B,C,128,128]
    const float* __restrict__ wgt,   // [B,C,5,5]
    const float* __restrict__ bias,  // [B,C]
    const float* __restrict__ sign,  // [B]
    float* __restrict__ out)         // [B,C,128,128]
{
    // persistent block = one full plane; T1 XCD-chunked (1024 % 8 == 0)
    const int bid = blockIdx.x;
    const int bc  = (bid & 7) * 128 + (bid >> 3);   // plane = b*64 + c
    const int b   = bc >> 6;

    float*       __restrict__ yp = out + (size_t)bc * (HH * WW);
    const float* __restrict__ wp = wgt + bc * 25;

    const float sgn = sign[b];
    const float s   = (fabsf(sgn) >= 1e-7f) ? sgn : 1.0f;
    const float bvs = bias[bc] * s;
    const __fp16 sh = (__fp16)s;
    const h2 s2 = { sh, sh };

    // weights as broadcast f16 pairs -> SGPRs (block-uniform)
    uint32_t wsu[25];
#pragma unroll
    for (int k = 0; k < 25; ++k) {
        const __fp16 wh = (__fp16)wp[k];
        h2 w2 = { wh, wh };
        wsu[k] = (uint32_t)__builtin_amdgcn_readfirstlane((int)h2u(w2));
    }

    const int t  = threadIdx.x;
    const int tx = t & 31;           // 4-col block: cols j0..j0+3
    const int ty = t >> 5;           // 0..7 (4-row subtile per 32-row band)
    const int j0 = tx * 4;
    const int planeOff = bc * (HH * WW);
    const bool mL = (tx > 0);
    const bool mR = (tx < 31);

    float4 vm[8];                    // rolling 8-load window (ring by row index)
    h2 acc0[4], acc1[4];             // re-first-touched each tile at p==0

    auto ISSUE = [&](int q, int r) {
        const int rrow = q * 32 + ty * 4 - 2 + r;
        const int rc   = min(max(rrow, 0), HH - 1);   // v_med3; masked in consume
        const float* gp = x + planeOff + rc * WW + j0;
        asm volatile("global_load_dwordx4 %0, %1, off" : "=v"(vm[r]) : "v"(gp));
    };

    auto CONSUME = [&](int q, int r8) {
        const int  i0   = q * 32 + ty * 4;
        const int  rrow = i0 - 2 + r8;
        const bool rv   = ((unsigned)rrow < (unsigned)HH);
        // own even pairs, row-masked (pad -> 0 -> tap fma(0,s,w) = w)
        uint32_t e1 = h2u(__builtin_amdgcn_cvt_pkrtz(vm[r8].x, vm[r8].y));
        uint32_t e2 = h2u(__builtin_amdgcn_cvt_pkrtz(vm[r8].z, vm[r8].w));
        e1 = rv ? e1 : 0u;
        e2 = rv ? e2 : 0u;
        // halo pairs from lane neighbors, col-masked
        uint32_t e0 = (uint32_t)__shfl_up((int)e2, 1, 32);
        uint32_t e3 = (uint32_t)__shfl_down((int)e1, 1, 32);
        e0 = mL ? e0 : 0u;
        e3 = mR ? e3 : 0u;
        const uint32_t o0 = __builtin_amdgcn_alignbit(e1, e0, 16);  // (-1,0)
        const uint32_t o1 = __builtin_amdgcn_alignbit(e2, e1, 16);  // (1,2)
        const uint32_t o2 = __builtin_amdgcn_alignbit(e3, e2, 16);  // (3,4)
        const uint32_t P0[5] = { e0, o0, e1, o1, e2 };
        const uint32_t P1[5] = { e1, o1, e2, o2, e3 };
#pragma unroll
        for (int p = 0; p < 5; ++p) {
            const int oi = r8 - p;
            if (oi >= 0 && oi < 4) {
                const h2 w0 = uh2(wsu[p * 5 + 0]);
                const h2 w1 = uh2(wsu[p * 5 + 1]);
                const h2 w2 = uh2(wsu[p * 5 + 2]);
                const h2 w3 = uh2(wsu[p * 5 + 3]);
                const h2 w4 = uh2(wsu[p * 5 + 4]);
                {
                    const h2 t0 = H2FMA(uh2(P0[0]), s2, w0);
                    const h2 t1 = H2FMA(uh2(P0[1]), s2, w1);
                    const h2 t2 = H2FMA(uh2(P0[2]), s2, w2);
                    const h2 t3 = H2FMA(uh2(P0[3]), s2, w3);
                    const h2 t4 = H2FMA(uh2(P0[4]), s2, w4);
                    h2 mm = h2max(h2max(h2max(t0, t1), h2max(t2, t3)), t4);
                    acc0[oi] = (p == 0) ? mm : h2max(acc0[oi], mm);
                }
                {
                    const h2 t0 = H2FMA(uh2(P1[0]), s2, w0);
                    const h2 t1 = H2FMA(uh2(P1[1]), s2, w1);
                    const h2 t2 = H2FMA(uh2(P1[2]), s2, w2);
                    const h2 t3 = H2FMA(uh2(P1[3]), s2, w3);
                    const h2 t4 = H2FMA(uh2(P1[4]), s2, w4);
                    h2 mm = h2max(h2max(h2max(t0, t1), h2max(t2, t3)), t4);
                    acc1[oi] = (p == 0) ? mm : h2max(acc1[oi], mm);
                }
            }
        }
    };

    auto STORE = [&](int q) {
        const int i0 = q * 32 + ty * 4;
#pragma unroll
        for (int a = 0; a < 4; ++a) {
            float4 o;
            o.x = fmaf((float)acc0[a][0], s, bvs);
            o.y = fmaf((float)acc0[a][1], s, bvs);
            o.z = fmaf((float)acc1[a][0], s, bvs);
            o.w = fmaf((float)acc1[a][1], s, bvs);
            *reinterpret_cast<float4*>(yp + (size_t)(i0 + a) * WW + j0) = o;
        }
    };

    // normalize vmcnt so the counted waits are exact
    asm volatile("s_waitcnt vmcnt(0)" ::: "memory");

    // ---- persistent cross-tile pipeline: constant 8-load window ----
    ISSUE(0,0); ISSUE(0,1); ISSUE(0,2); ISSUE(0,3);
    ISSUE(0,4); ISSUE(0,5); ISSUE(0,6); ISSUE(0,7);

    // tile 0 (issues tile 1)
    WAITV(7); CONSUME(0,0); ISSUE(1,0);
    WAITV(7); CONSUME(0,1); ISSUE(1,1);
    WAITV(7); CONSUME(0,2); ISSUE(1,2);
    WAITV(7); CONSUME(0,3); ISSUE(1,3);
    WAITV(7); CONSUME(0,4); ISSUE(1,4);
    WAITV(7); CONSUME(0,5); ISSUE(1,5);
    WAITV(7); CONSUME(0,6); ISSUE(1,6);
    WAITV(7); CONSUME(0,7); ISSUE(1,7);
    STORE(0);
    // tile 1 (issues tile 2); WAITV(7) stays safe with <=4 stores in FIFO
    WAITV(7); CONSUME(1,0); ISSUE(2,0);
    WAITV(7); CONSUME(1,1); ISSUE(2,1);
    WAITV(7); CONSUME(1,2); ISSUE(2,2);
    WAITV(7); CONSUME(1,3); ISSUE(2,3);
    WAITV(7); CONSUME(1,4); ISSUE(2,4);
    WAITV(7); CONSUME(1,5); ISSUE(2,5);
    WAITV(7); CONSUME(1,6); ISSUE(2,6);
    WAITV(7); CONSUME(1,7); ISSUE(2,7);
    STORE(1);
    // tile 2 (issues tile 3)
    WAITV(7); CONSUME(2,0); ISSUE(3,0);
    WAITV(7); CONSUME(2,1); ISSUE(3,1);
    WAITV(7); CONSUME(2,2); ISSUE(3,2);
    WAITV(7); CONSUME(2,3); ISSUE(3,3);
    WAITV(7); CONSUME(2,4); ISSUE(3,4);
    WAITV(7); CONSUME(2,5); ISSUE(3,5);
    WAITV(7); CONSUME(2,6); ISSUE(3,6);
    WAITV(7); CONSUME(2,7); ISSUE(3,7);
    STORE(2);
    // tile 3 drain (WAITV(7-r) also drains lingering stores)
    WAITV(7); CONSUME(3,0);
    WAITV(6); CONSUME(3,1);
    WAITV(5); CONSUME(3,2);
    WAITV(4); CONSUME(3,3);
    WAITV(3); CONSUME(3,4);
    WAITV(2); CONSUME(3,5);
    WAITV(1); CONSUME(3,6);
    WAITV(0); CONSUME(3,7);
    STORE(3);
}

extern "C" void kernel_launch(void* const* d_in, const int* in_sizes, int n_in,
                              void* d_out, int out_size, void* d_ws, size_t ws_size,
                              hipStream_t stream) {
    (void)d_ws; (void)ws_size; (void)in_sizes; (void)n_in; (void)out_size;
    const float* x    = (const float*)d_in[0];
    const float* w    = (const float*)d_in[1];
    const float* bias = (const float*)d_in[2];
    const float* sign = (const float*)d_in[3];
    float* out = (float*)d_out;

    morpho_kernel<<<1024, 256, 0, stream>>>(x, w, bias, sign, out);
}

// Round 16
// 27.310 us; speedup vs baseline: 1.1963x; 1.0061x over previous
//
#include <hip/hip_runtime.h>
#include <math.h>
#include <stdint.h>

#define HH 128
#define WW 128

typedef __fp16 h2 __attribute__((ext_vector_type(2)));

__device__ __forceinline__ h2 h2max(h2 a, h2 b) { return __builtin_elementwise_max(a, b); }
__device__ __forceinline__ uint32_t h2u(h2 v) { return __builtin_bit_cast(uint32_t, v); }
__device__ __forceinline__ h2 uh2(uint32_t v) { return __builtin_bit_cast(h2, v); }

#if __has_builtin(__builtin_elementwise_fma)
#define H2FMA(a, b, c) __builtin_elementwise_fma((a), (b), (c))
#else
#define H2FMA(a, b, c) ((a) * (b) + (c))   // contracts to v_pk_fma_f16
#endif

// counted wait + scheduling fence (rule #18)
#define WAITV(n) do { asm volatile("s_waitcnt vmcnt(" #n ")" ::: "memory"); \
                      __builtin_amdgcn_sched_barrier(0); } while (0)

__global__ __launch_bounds__(256) void morpho_kernel(
    const float* __restrict__ x,     // [B,C,128,128]
    const float* __restrict__ wgt,   // [B,C,5,5]
    const float* __restrict__ bias,  // [B,C]
    const float* __restrict__ sign,  // [B]
    float* __restrict__ out)         // [B,C,128,128]
{
    // persistent block = one full plane; T1 XCD-chunked (1024 % 8 == 0)
    const int bid = blockIdx.x;
    const int bc  = (bid & 7) * 128 + (bid >> 3);   // plane = b*64 + c
    const int b   = bc >> 6;

    float*       __restrict__ yp = out + (size_t)bc * (HH * WW);
    const float* __restrict__ wp = wgt + bc * 25;

    const float sgn = sign[b];
    const float s   = (fabsf(sgn) >= 1e-7f) ? sgn : 1.0f;
    const float bvs = bias[bc] * s;
    const __fp16 sh = (__fp16)s;
    const h2 s2 = { sh, sh };

    // weights as broadcast f16 pairs -> SGPRs (block-uniform)
    uint32_t wsu[25];
#pragma unroll
    for (int k = 0; k < 25; ++k) {
        const __fp16 wh = (__fp16)wp[k];
        h2 w2 = { wh, wh };
        wsu[k] = (uint32_t)__builtin_amdgcn_readfirstlane((int)h2u(w2));
    }

    const int t   = threadIdx.x;
    const int tx  = t & 31;          // 4-col block: cols j0..j0+3
    const int ty4 = (t >> 5) * 4;    // first output row of subtile within band
    const int j0  = tx * 4;
    const float* __restrict__ xcb = x + bc * (HH * WW) + j0;  // col base
    const bool mL = (tx > 0);
    const bool mR = (tx < 31);

    float4 vm[8];                    // rolling 8-load window
    h2 acc0[4], acc1[4];             // re-first-touched each tile at p==0

    // clampRow is a literal at every call site -> folds away for interior rows
    auto ISSUE = [&](int q, int r, bool clampRow) {
        int rrow = q * 32 + ty4 - 2 + r;
        if (clampRow) rrow = min(max(rrow, 0), HH - 1);
        const float* gp = xcb + rrow * WW;
        asm volatile("global_load_dwordx4 %0, %1, off" : "=v"(vm[r]) : "v"(gp));
    };

    auto CONSUME = [&](int q, int r8, bool rowmask) {
        bool rv = true;
        if (rowmask) {
            const int rrow = q * 32 + ty4 - 2 + r8;
            rv = ((unsigned)rrow < (unsigned)HH);
        }
        uint32_t e1 = h2u(__builtin_amdgcn_cvt_pkrtz(vm[r8].x, vm[r8].y));
        uint32_t e2 = h2u(__builtin_amdgcn_cvt_pkrtz(vm[r8].z, vm[r8].w));
        if (rowmask) { e1 = rv ? e1 : 0u; e2 = rv ? e2 : 0u; }
        uint32_t e0 = (uint32_t)__shfl_up((int)e2, 1, 32);
        uint32_t e3 = (uint32_t)__shfl_down((int)e1, 1, 32);
        e0 = mL ? e0 : 0u;
        e3 = mR ? e3 : 0u;
        const uint32_t o0 = __builtin_amdgcn_alignbit(e1, e0, 16);  // (-1,0)
        const uint32_t o1 = __builtin_amdgcn_alignbit(e2, e1, 16);  // (1,2)
        const uint32_t o2 = __builtin_amdgcn_alignbit(e3, e2, 16);  // (3,4)
        const uint32_t P0[5] = { e0, o0, e1, o1, e2 };
        const uint32_t P1[5] = { e1, o1, e2, o2, e3 };
#pragma unroll
        for (int p = 0; p < 5; ++p) {
            const int oi = r8 - p;
            if (oi >= 0 && oi < 4) {
                const h2 w0 = uh2(wsu[p * 5 + 0]);
                const h2 w1 = uh2(wsu[p * 5 + 1]);
                const h2 w2 = uh2(wsu[p * 5 + 2]);
                const h2 w3 = uh2(wsu[p * 5 + 3]);
                const h2 w4 = uh2(wsu[p * 5 + 4]);
                {
                    const h2 t0 = H2FMA(uh2(P0[0]), s2, w0);
                    const h2 t1 = H2FMA(uh2(P0[1]), s2, w1);
                    const h2 t2 = H2FMA(uh2(P0[2]), s2, w2);
                    const h2 t3 = H2FMA(uh2(P0[3]), s2, w3);
                    const h2 t4 = H2FMA(uh2(P0[4]), s2, w4);
                    h2 mm = h2max(h2max(h2max(t0, t1), h2max(t2, t3)), t4);
                    acc0[oi] = (p == 0) ? mm : h2max(acc0[oi], mm);
                }
                {
                    const h2 t0 = H2FMA(uh2(P1[0]), s2, w0);
                    const h2 t1 = H2FMA(uh2(P1[1]), s2, w1);
                    const h2 t2 = H2FMA(uh2(P1[2]), s2, w2);
                    const h2 t3 = H2FMA(uh2(P1[3]), s2, w3);
                    const h2 t4 = H2FMA(uh2(P1[4]), s2, w4);
                    h2 mm = h2max(h2max(h2max(t0, t1), h2max(t2, t3)), t4);
                    acc1[oi] = (p == 0) ? mm : h2max(acc1[oi], mm);
                }
            }
        }
    };

    // row a of tile q is final after CONSUME(q, a+4) -> store immediately
    auto STORE_ROW = [&](int q, int a) {
        float4 o;
        o.x = fmaf((float)acc0[a][0], s, bvs);
        o.y = fmaf((float)acc0[a][1], s, bvs);
        o.z = fmaf((float)acc1[a][0], s, bvs);
        o.w = fmaf((float)acc1[a][1], s, bvs);
        *reinterpret_cast<float4*>(yp + (size_t)(q * 32 + ty4 + a) * WW + j0) = o;
    };

    // normalize vmcnt so the counted waits are exact
    asm volatile("s_waitcnt vmcnt(0)" ::: "memory");

    // ---- prologue: tile 0's 8 loads (rows -2,-1 clamped) ----
    ISSUE(0,0,true); ISSUE(0,1,true);
    ISSUE(0,2,false); ISSUE(0,3,false); ISSUE(0,4,false);
    ISSUE(0,5,false); ISSUE(0,6,false); ISSUE(0,7,false);

    // tile 0 (issues tile 1; rows -2,-1 masked)
    WAITV(7); CONSUME(0,0,true);  ISSUE(1,0,false);
    WAITV(7); CONSUME(0,1,true);  ISSUE(1,1,false);
    WAITV(7); CONSUME(0,2,false); ISSUE(1,2,false);
    WAITV(7); CONSUME(0,3,false); ISSUE(1,3,false);
    WAITV(7); CONSUME(0,4,false); ISSUE(1,4,false); STORE_ROW(0,0);
    WAITV(7); CONSUME(0,5,false); ISSUE(1,5,false); STORE_ROW(0,1);
    WAITV(7); CONSUME(0,6,false); ISSUE(1,6,false); STORE_ROW(0,2);
    WAITV(7); CONSUME(0,7,false); ISSUE(1,7,false); STORE_ROW(0,3);
    // tile 1 (issues tile 2)
    WAITV(7); CONSUME(1,0,false); ISSUE(2,0,false);
    WAITV(7); CONSUME(1,1,false); ISSUE(2,1,false);
    WAITV(7); CONSUME(1,2,false); ISSUE(2,2,false);
    WAITV(7); CONSUME(1,3,false); ISSUE(2,3,false);
    WAITV(7); CONSUME(1,4,false); ISSUE(2,4,false); STORE_ROW(1,0);
    WAITV(7); CONSUME(1,5,false); ISSUE(2,5,false); STORE_ROW(1,1);
    WAITV(7); CONSUME(1,6,false); ISSUE(2,6,false); STORE_ROW(1,2);
    WAITV(7); CONSUME(1,7,false); ISSUE(2,7,false); STORE_ROW(1,3);
    // tile 2 (issues tile 3; rows 128,129 clamped)
    WAITV(7); CONSUME(2,0,false); ISSUE(3,0,false);
    WAITV(7); CONSUME(2,1,false); ISSUE(3,1,false);
    WAITV(7); CONSUME(2,2,false); ISSUE(3,2,false);
    WAITV(7); CONSUME(2,3,false); ISSUE(3,3,false);
    WAITV(7); CONSUME(2,4,false); ISSUE(3,4,false); STORE_ROW(2,0);
    WAITV(7); CONSUME(2,5,false); ISSUE(3,5,false); STORE_ROW(2,1);
    WAITV(7); CONSUME(2,6,false); ISSUE(3,6,true);  STORE_ROW(2,2);
    WAITV(7); CONSUME(2,7,false); ISSUE(3,7,true);  STORE_ROW(2,3);
    // tile 3 drain (rows 128,129 masked); WAITV(7-r) stays exact w/ stores (FIFO retire)
    WAITV(7); CONSUME(3,0,false);
    WAITV(6); CONSUME(3,1,false);
    WAITV(5); CONSUME(3,2,false);
    WAITV(4); CONSUME(3,3,false);
    WAITV(3); CONSUME(3,4,false);                   STORE_ROW(3,0);
    WAITV(2); CONSUME(3,5,false);                   STORE_ROW(3,1);
    WAITV(1); CONSUME(3,6,true);                    STORE_ROW(3,2);
    WAITV(0); CONSUME(3,7,true);                    STORE_ROW(3,3);
}

extern "C" void kernel_launch(void* const* d_in, const int* in_sizes, int n_in,
                              void* d_out, int out_size, void* d_ws, size_t ws_size,
                              hipStream_t stream) {
    (void)d_ws; (void)ws_size; (void)in_sizes; (void)n_in; (void)out_size;
    const float* x    = (const float*)d_in[0];
    const float* w    = (const float*)d_in[1];
    const float* bias = (const float*)d_in[2];
    const float* sign = (const float*)d_in[3];
    float* out = (float*)d_out;

    morpho_kernel<<<1024, 256, 0, stream>>>(x, w, bias, sign, out);
}